// Round 1
// baseline (274.925 us; speedup 1.0000x reference)
//
#include <hip/hip_runtime.h>
#include <math.h>

#define BATCH 8
#define SEQ   4096
#define DIM   1024

// ---------------------------------------------------------------------------
// Kernel A: q0[b,e] = dot(x[b,0,:], Wq[e,:]) + bq[e]
// grid (DIM/4, BATCH), block 256 = 4 waves; wave w computes e = bx*4 + w.
// Lanes split the 1024-dim dot as 4x float4 each (coalesced Wq row reads).
// ---------------------------------------------------------------------------
__global__ void qrow_kernel(const float* __restrict__ x,
                            const float* __restrict__ Wq,
                            const float* __restrict__ bq,
                            float* __restrict__ q0) {
    __shared__ float xs[DIM];
    const int b   = blockIdx.y;
    const int tid = threadIdx.x;

    // stage x[b,0,:] (4 KB) into LDS: 256 threads x float4
    ((float4*)xs)[tid] = ((const float4*)(x + (size_t)b * SEQ * DIM))[tid];
    __syncthreads();

    const int wave = tid >> 6;
    const int lane = tid & 63;
    const int e    = blockIdx.x * 4 + wave;

    const float4* wrow = (const float4*)(Wq + (size_t)e * DIM);
    float acc = 0.f;
#pragma unroll
    for (int i = 0; i < 4; ++i) {
        const int idx = i * 64 + lane;      // 256 float4s per row
        float4 wv = wrow[idx];
        float4 xv = ((const float4*)xs)[idx];
        acc += wv.x * xv.x + wv.y * xv.y + wv.z * xv.z + wv.w * xv.w;
    }
#pragma unroll
    for (int off = 32; off > 0; off >>= 1)
        acc += __shfl_down(acc, off, 64);

    if (lane == 0) q0[b * DIM + e] = acc + bq[e];
}

// ---------------------------------------------------------------------------
// Kernel B: v[b,d] = sum_e q0[b,e] * Wk[e,d]   (q0 @ Wk; Wk column walk is
// coalesced since consecutive threads take consecutive d).
// grid (DIM/256, BATCH), block 256.
// ---------------------------------------------------------------------------
__global__ void vvec_kernel(const float* __restrict__ q0,
                            const float* __restrict__ Wk,
                            float* __restrict__ v) {
    __shared__ float qs[DIM];
    const int b   = blockIdx.y;
    const int tid = threadIdx.x;

    ((float4*)qs)[tid] = ((const float4*)(q0 + b * DIM))[tid];
    __syncthreads();

    const int d = blockIdx.x * 256 + tid;
    float acc = 0.f;
#pragma unroll 8
    for (int e = 0; e < DIM; ++e)
        acc += qs[e] * Wk[(size_t)e * DIM + d];   // qs[e] is an LDS broadcast
    v[b * DIM + d] = acc;
}

// ---------------------------------------------------------------------------
// Kernel C: s[b,m] = dot(v[b,:], x[b,m,:])  -> written into d_out as raw
// scores. grid (SEQ/16, BATCH), block 256 = 4 waves, each wave does 4 rows.
// This is THE memory-bound kernel (reads all of x once: 128 MiB).
// ---------------------------------------------------------------------------
__global__ void score_kernel(const float* __restrict__ x,
                             const float* __restrict__ v,
                             float* __restrict__ s) {
    __shared__ float vs[DIM];
    const int b   = blockIdx.y;
    const int tid = threadIdx.x;

    ((float4*)vs)[tid] = ((const float4*)(v + b * DIM))[tid];
    __syncthreads();

    const int wave = tid >> 6;
    const int lane = tid & 63;

    // each lane's 4 float4 fragments of v, reused across 4 rows
    float4 vf[4];
#pragma unroll
    for (int i = 0; i < 4; ++i) vf[i] = ((const float4*)vs)[i * 64 + lane];

    const float4* xb = (const float4*)(x + (size_t)b * SEQ * DIM);
#pragma unroll
    for (int r = 0; r < 4; ++r) {
        const int m = blockIdx.x * 16 + wave * 4 + r;
        const float4* xrow = xb + (size_t)m * (DIM / 4);
        float acc = 0.f;
#pragma unroll
        for (int i = 0; i < 4; ++i) {
            float4 xv = xrow[i * 64 + lane];   // coalesced 1 KB/wave/instr
            acc += vf[i].x * xv.x + vf[i].y * xv.y + vf[i].z * xv.z + vf[i].w * xv.w;
        }
#pragma unroll
        for (int off = 32; off > 0; off >>= 1)
            acc += __shfl_down(acc, off, 64);
        if (lane == 0) s[b * SEQ + m] = acc;
    }
}

// ---------------------------------------------------------------------------
// Kernel D: softmax over m for each b, in place on d_out.
// grid BATCH, block 256; each thread owns 16 strided elements (registers),
// so in-place is safe: all reads precede the barrier, writes follow it.
// ---------------------------------------------------------------------------
__global__ void softmax_kernel(float* __restrict__ s) {
    __shared__ float red[4];
    const int b    = blockIdx.x;
    const int tid  = threadIdx.x;
    const int wave = tid >> 6;
    const int lane = tid & 63;

    float vals[16];
    float mx = -INFINITY;
#pragma unroll
    for (int i = 0; i < 16; ++i) {
        vals[i] = s[b * SEQ + i * 256 + tid];
        mx = fmaxf(mx, vals[i]);
    }
#pragma unroll
    for (int off = 32; off > 0; off >>= 1)
        mx = fmaxf(mx, __shfl_xor(mx, off, 64));
    if (lane == 0) red[wave] = mx;
    __syncthreads();
    mx = fmaxf(fmaxf(red[0], red[1]), fmaxf(red[2], red[3]));

    float sum = 0.f;
#pragma unroll
    for (int i = 0; i < 16; ++i) {
        vals[i] = expf(vals[i] - mx);
        sum += vals[i];
    }
#pragma unroll
    for (int off = 32; off > 0; off >>= 1)
        sum += __shfl_xor(sum, off, 64);
    __syncthreads();                 // red[] reuse
    if (lane == 0) red[wave] = sum;
    __syncthreads();
    sum = red[0] + red[1] + red[2] + red[3];

    const float inv = 1.f / sum;
#pragma unroll
    for (int i = 0; i < 16; ++i)
        s[b * SEQ + i * 256 + tid] = vals[i] * inv;
}

// ---------------------------------------------------------------------------
extern "C" void kernel_launch(void* const* d_in, const int* in_sizes, int n_in,
                              void* d_out, int out_size, void* d_ws, size_t ws_size,
                              hipStream_t stream) {
    const float* x  = (const float*)d_in[0];
    const float* Wq = (const float*)d_in[1];
    const float* bq = (const float*)d_in[2];
    const float* Wk = (const float*)d_in[3];
    // d_in[4] = bk: unused — its contribution is constant over m, and softmax
    // is shift-invariant.

    float* out = (float*)d_out;                 // [BATCH, SEQ]
    float* q0  = (float*)d_ws;                  // BATCH*DIM floats (32 KB)
    float* v   = q0 + BATCH * DIM;              // BATCH*DIM floats (32 KB)

    qrow_kernel<<<dim3(DIM / 4, BATCH), 256, 0, stream>>>(x, Wq, bq, q0);
    vvec_kernel<<<dim3(DIM / 256, BATCH), 256, 0, stream>>>(q0, Wk, v);
    score_kernel<<<dim3(SEQ / 16, BATCH), 256, 0, stream>>>(x, v, out);
    softmax_kernel<<<BATCH, 256, 0, stream>>>(out);
}

// Round 2
// 217.313 us; speedup vs baseline: 1.2651x; 1.2651x over previous
//
#include <hip/hip_runtime.h>
#include <math.h>

#define BATCH 8
#define SEQ   4096
#define DIM   1024

// ---------------------------------------------------------------------------
// Kernel A: q0[b,e] = dot(x[b,0,:], Wq[e,:]) + bq[e]
// grid (DIM/4, BATCH), block 256 = 4 waves; wave w computes e = bx*4 + w.
// ---------------------------------------------------------------------------
__global__ __launch_bounds__(256) void qrow_kernel(const float* __restrict__ x,
                            const float* __restrict__ Wq,
                            const float* __restrict__ bq,
                            float* __restrict__ q0) {
    __shared__ float xs[DIM];
    const int b   = blockIdx.y;
    const int tid = threadIdx.x;

    ((float4*)xs)[tid] = ((const float4*)(x + (size_t)b * SEQ * DIM))[tid];
    __syncthreads();

    const int wave = tid >> 6;
    const int lane = tid & 63;
    const int e    = blockIdx.x * 4 + wave;

    const float4* wrow = (const float4*)(Wq + (size_t)e * DIM);
    float acc = 0.f;
#pragma unroll
    for (int i = 0; i < 4; ++i) {
        const int idx = i * 64 + lane;
        float4 wv = wrow[idx];
        float4 xv = ((const float4*)xs)[idx];
        acc += wv.x * xv.x + wv.y * xv.y + wv.z * xv.z + wv.w * xv.w;
    }
#pragma unroll
    for (int off = 32; off > 0; off >>= 1)
        acc += __shfl_down(acc, off, 64);

    if (lane == 0) q0[b * DIM + e] = acc + bq[e];
}

// ---------------------------------------------------------------------------
// Kernel B: v[b,d] = sum_e q0[b,e] * Wk[e,d]
// v2: grid (DIM/128, BATCH) = 64 blocks, 1024 threads (16 waves).
// e-dim split 8-ways across thread groups (128 iters/thread instead of 1024),
// LDS partial-reduce at the end. Kills the R0 latency-bound 32-block design.
// ---------------------------------------------------------------------------
__global__ __launch_bounds__(1024) void vvec_kernel(const float* __restrict__ q0,
                            const float* __restrict__ Wk,
                            float* __restrict__ v) {
    __shared__ float qs[DIM];
    __shared__ float ps[1024];
    const int b   = blockIdx.y;
    const int tid = threadIdx.x;

    qs[tid] = q0[b * DIM + tid];
    __syncthreads();

    const int dl = tid & 127;                  // 128 d's per block
    const int ec = tid >> 7;                   // 8 e-chunks of 128
    const int d  = blockIdx.x * 128 + dl;

    const float* wcol = Wk + (size_t)(ec * 128) * DIM + d;
    float acc = 0.f;
#pragma unroll 8
    for (int i = 0; i < 128; ++i)
        acc += qs[ec * 128 + i] * wcol[(size_t)i * DIM];   // coalesced over dl

    ps[tid] = acc;
    __syncthreads();

    if (tid < 128) {
        float s = 0.f;
#pragma unroll
        for (int e8 = 0; e8 < 8; ++e8) s += ps[e8 * 128 + tid];
        v[b * DIM + blockIdx.x * 128 + tid] = s;
    }
}

// ---------------------------------------------------------------------------
// Kernel C: s[b,m] = dot(v[b,:], x[b,m,:])  — THE memory-bound kernel
// (reads all of x once: 134 MB -> ~21 us floor). grid (SEQ/16, BATCH),
// block 256 = 4 waves x 4 rows each.
// ---------------------------------------------------------------------------
__global__ __launch_bounds__(256) void score_kernel(const float* __restrict__ x,
                             const float* __restrict__ v,
                             float* __restrict__ s) {
    __shared__ float vs[DIM];
    const int b   = blockIdx.y;
    const int tid = threadIdx.x;

    ((float4*)vs)[tid] = ((const float4*)(v + b * DIM))[tid];
    __syncthreads();

    const int wave = tid >> 6;
    const int lane = tid & 63;

    float4 vf[4];
#pragma unroll
    for (int i = 0; i < 4; ++i) vf[i] = ((const float4*)vs)[i * 64 + lane];

    const float4* xb = (const float4*)(x + (size_t)b * SEQ * DIM);
#pragma unroll
    for (int r = 0; r < 4; ++r) {
        const int m = blockIdx.x * 16 + wave * 4 + r;
        const float4* xrow = xb + (size_t)m * (DIM / 4);
        float acc = 0.f;
#pragma unroll
        for (int i = 0; i < 4; ++i) {
            float4 xv = xrow[i * 64 + lane];
            acc += vf[i].x * xv.x + vf[i].y * xv.y + vf[i].z * xv.z + vf[i].w * xv.w;
        }
#pragma unroll
        for (int off = 32; off > 0; off >>= 1)
            acc += __shfl_down(acc, off, 64);
        if (lane == 0) s[b * SEQ + m] = acc;
    }
}

// ---------------------------------------------------------------------------
// Kernel D: softmax over m per batch, in place. v2: 1024 threads/block,
// 4 elems/thread (was 16), 16-wave LDS reduce — cuts the latency tail.
// ---------------------------------------------------------------------------
__global__ __launch_bounds__(1024) void softmax_kernel(float* __restrict__ s) {
    __shared__ float red[16];
    const int b    = blockIdx.x;
    const int tid  = threadIdx.x;
    const int wave = tid >> 6;
    const int lane = tid & 63;

    float vals[4];
    float mx = -INFINITY;
#pragma unroll
    for (int i = 0; i < 4; ++i) {
        vals[i] = s[b * SEQ + i * 1024 + tid];
        mx = fmaxf(mx, vals[i]);
    }
#pragma unroll
    for (int off = 32; off > 0; off >>= 1)
        mx = fmaxf(mx, __shfl_xor(mx, off, 64));
    if (lane == 0) red[wave] = mx;
    __syncthreads();
#pragma unroll
    for (int w = 0; w < 16; ++w) mx = fmaxf(mx, red[w]);

    float sum = 0.f;
#pragma unroll
    for (int i = 0; i < 4; ++i) {
        vals[i] = expf(vals[i] - mx);
        sum += vals[i];
    }
#pragma unroll
    for (int off = 32; off > 0; off >>= 1)
        sum += __shfl_xor(sum, off, 64);
    __syncthreads();                 // red[] reuse
    if (lane == 0) red[wave] = sum;
    __syncthreads();
    sum = 0.f;
#pragma unroll
    for (int w = 0; w < 16; ++w) sum += red[w];

    const float inv = 1.f / sum;
#pragma unroll
    for (int i = 0; i < 4; ++i)
        s[b * SEQ + i * 1024 + tid] = vals[i] * inv;
}

// ---------------------------------------------------------------------------
extern "C" void kernel_launch(void* const* d_in, const int* in_sizes, int n_in,
                              void* d_out, int out_size, void* d_ws, size_t ws_size,
                              hipStream_t stream) {
    const float* x  = (const float*)d_in[0];
    const float* Wq = (const float*)d_in[1];
    const float* bq = (const float*)d_in[2];
    const float* Wk = (const float*)d_in[3];
    // d_in[4] = bk: constant over m after the q0 dot -> softmax-shift-invariant,
    // dropped entirely.

    float* out = (float*)d_out;                 // [BATCH, SEQ]
    float* q0  = (float*)d_ws;                  // BATCH*DIM floats
    float* v   = q0 + BATCH * DIM;              // BATCH*DIM floats

    qrow_kernel<<<dim3(DIM / 4, BATCH), 256, 0, stream>>>(x, Wq, bq, q0);
    vvec_kernel<<<dim3(DIM / 128, BATCH), 1024, 0, stream>>>(q0, Wk, v);
    score_kernel<<<dim3(SEQ / 16, BATCH), 256, 0, stream>>>(x, v, out);
    softmax_kernel<<<BATCH, 1024, 0, stream>>>(out);
}

// Round 3
// 213.435 us; speedup vs baseline: 1.2881x; 1.0182x over previous
//
#include <hip/hip_runtime.h>
#include <math.h>

#define BATCH 8
#define SEQ   4096
#define DIM   1024

// ---------------------------------------------------------------------------
// Kernel A: q0[b,e] = dot(x[b,0,:], Wq[e,:]) + bq[e]   for ALL 8 batches.
// v3: batch-fused — stage all 8 x-rows (32 KB LDS), read Wq ONCE (4 MB, was
// 32 MB with grid.y=8). grid DIM/4 = 256 blocks, block 256 = 4 waves, wave w
// owns row e = bx*4 + w and computes 8 dots against the staged x-rows.
// ---------------------------------------------------------------------------
__global__ __launch_bounds__(256) void qrow_kernel(const float* __restrict__ x,
                            const float* __restrict__ Wq,
                            const float* __restrict__ bq,
                            float* __restrict__ q0) {
    __shared__ float xs[BATCH][DIM];            // 32 KB
    const int tid = threadIdx.x;

#pragma unroll
    for (int b = 0; b < BATCH; ++b)             // 8 coalesced 4 KB row stages
        ((float4*)xs[b])[tid] = ((const float4*)(x + (size_t)b * SEQ * DIM))[tid];
    __syncthreads();

    const int wave = tid >> 6;
    const int lane = tid & 63;
    const int e    = blockIdx.x * 4 + wave;

    const float4* wrow = (const float4*)(Wq + (size_t)e * DIM);
    float4 wv[4];
#pragma unroll
    for (int i = 0; i < 4; ++i) wv[i] = wrow[i * 64 + lane];

    float acc[BATCH];
#pragma unroll
    for (int b = 0; b < BATCH; ++b) {
        float a = 0.f;
#pragma unroll
        for (int i = 0; i < 4; ++i) {
            float4 xv = ((const float4*)xs[b])[i * 64 + lane];
            a += wv[i].x * xv.x + wv[i].y * xv.y + wv[i].z * xv.z + wv[i].w * xv.w;
        }
        acc[b] = a;
    }
#pragma unroll
    for (int b = 0; b < BATCH; ++b) {
#pragma unroll
        for (int off = 32; off > 0; off >>= 1)
            acc[b] += __shfl_down(acc[b], off, 64);
    }
    if (lane == 0) {
        const float bqe = bq[e];
#pragma unroll
        for (int b = 0; b < BATCH; ++b)
            q0[b * DIM + e] = acc[b] + bqe;
    }
}

// ---------------------------------------------------------------------------
// Kernel B: v[b,d] = sum_e q0[b,e] * Wk[e,d]   for ALL 8 batches.
// v3: batch-fused — Wk read ONCE (4 MB, was 32 MB). grid DIM/64 = 16 blocks,
// block 1024 = 16 e-chunks x 64 d. Each thread: 64 e-iters, 8 batch-FMAs per
// Wk element (qs[b][e] is wave-uniform -> LDS broadcast, free). Partial sums
// reduced via ps[ec][b][dl] (bank-conflict-free: lanes map 2/bank).
// ---------------------------------------------------------------------------
__global__ __launch_bounds__(1024) void vvec_kernel(const float* __restrict__ q0,
                            const float* __restrict__ Wk,
                            float* __restrict__ v) {
    __shared__ float qs[BATCH][DIM];            // 32 KB
    __shared__ float ps[16][BATCH][64];         // 32 KB
    const int tid = threadIdx.x;

#pragma unroll
    for (int i = 0; i < 2; ++i)                 // 8192 floats = 2048 float4
        ((float4*)&qs[0][0])[i * 1024 + tid] = ((const float4*)q0)[i * 1024 + tid];
    __syncthreads();

    const int dl = tid & 63;
    const int ec = tid >> 6;                    // 0..15
    const int d  = blockIdx.x * 64 + dl;

    const float* wp = Wk + (size_t)(ec * 64) * DIM + d;
    float acc[BATCH] = {0.f, 0.f, 0.f, 0.f, 0.f, 0.f, 0.f, 0.f};
#pragma unroll 8
    for (int i = 0; i < 64; ++i) {
        const float w = wp[(size_t)i * DIM];    // coalesced over dl
#pragma unroll
        for (int b = 0; b < BATCH; ++b)
            acc[b] += qs[b][ec * 64 + i] * w;   // wave-uniform broadcast
    }
#pragma unroll
    for (int b = 0; b < BATCH; ++b) ps[ec][b][dl] = acc[b];
    __syncthreads();

    if (tid < BATCH * 64) {                     // 512 threads finish
        const int b = tid >> 6, dd = tid & 63;
        float s = 0.f;
#pragma unroll
        for (int e = 0; e < 16; ++e) s += ps[e][b][dd];
        v[b * DIM + blockIdx.x * 64 + dd] = s;
    }
}

// ---------------------------------------------------------------------------
// Kernel C: s[b,m] = dot(v[b,:], x[b,m,:])  — THE memory-bound kernel
// (reads all of x once: 134 MB -> ~20 us floor at achieved BW).
// grid (SEQ/16, BATCH), block 256 = 4 waves x 4 rows each.
// ---------------------------------------------------------------------------
__global__ __launch_bounds__(256) void score_kernel(const float* __restrict__ x,
                             const float* __restrict__ v,
                             float* __restrict__ s) {
    __shared__ float vs[DIM];
    const int b   = blockIdx.y;
    const int tid = threadIdx.x;

    ((float4*)vs)[tid] = ((const float4*)(v + b * DIM))[tid];
    __syncthreads();

    const int wave = tid >> 6;
    const int lane = tid & 63;

    float4 vf[4];
#pragma unroll
    for (int i = 0; i < 4; ++i) vf[i] = ((const float4*)vs)[i * 64 + lane];

    const float4* xb = (const float4*)(x + (size_t)b * SEQ * DIM);
#pragma unroll
    for (int r = 0; r < 4; ++r) {
        const int m = blockIdx.x * 16 + wave * 4 + r;
        const float4* xrow = xb + (size_t)m * (DIM / 4);
        float acc = 0.f;
#pragma unroll
        for (int i = 0; i < 4; ++i) {
            float4 xv = xrow[i * 64 + lane];    // 16 independent loads in flight
            acc += vf[i].x * xv.x + vf[i].y * xv.y + vf[i].z * xv.z + vf[i].w * xv.w;
        }
#pragma unroll
        for (int off = 32; off > 0; off >>= 1)
            acc += __shfl_down(acc, off, 64);
        if (lane == 0) s[b * SEQ + m] = acc;
    }
}

// ---------------------------------------------------------------------------
// Kernel D: softmax over m per batch, in place on d_out.
// 1024 threads/block, 4 elems/thread in registers (in-place safe: each thread
// writes only what it read), 16-wave LDS reduce.
// ---------------------------------------------------------------------------
__global__ __launch_bounds__(1024) void softmax_kernel(float* __restrict__ s) {
    __shared__ float red[16];
    const int b    = blockIdx.x;
    const int tid  = threadIdx.x;
    const int wave = tid >> 6;
    const int lane = tid & 63;

    float vals[4];
    float mx = -INFINITY;
#pragma unroll
    for (int i = 0; i < 4; ++i) {
        vals[i] = s[b * SEQ + i * 1024 + tid];
        mx = fmaxf(mx, vals[i]);
    }
#pragma unroll
    for (int off = 32; off > 0; off >>= 1)
        mx = fmaxf(mx, __shfl_xor(mx, off, 64));
    if (lane == 0) red[wave] = mx;
    __syncthreads();
#pragma unroll
    for (int w = 0; w < 16; ++w) mx = fmaxf(mx, red[w]);

    float sum = 0.f;
#pragma unroll
    for (int i = 0; i < 4; ++i) {
        vals[i] = expf(vals[i] - mx);
        sum += vals[i];
    }
#pragma unroll
    for (int off = 32; off > 0; off >>= 1)
        sum += __shfl_xor(sum, off, 64);
    __syncthreads();                 // red[] reuse
    if (lane == 0) red[wave] = sum;
    __syncthreads();
    sum = 0.f;
#pragma unroll
    for (int w = 0; w < 16; ++w) sum += red[w];

    const float inv = 1.f / sum;
#pragma unroll
    for (int i = 0; i < 4; ++i)
        s[b * SEQ + i * 1024 + tid] = vals[i] * inv;
}

// ---------------------------------------------------------------------------
extern "C" void kernel_launch(void* const* d_in, const int* in_sizes, int n_in,
                              void* d_out, int out_size, void* d_ws, size_t ws_size,
                              hipStream_t stream) {
    const float* x  = (const float*)d_in[0];
    const float* Wq = (const float*)d_in[1];
    const float* bq = (const float*)d_in[2];
    const float* Wk = (const float*)d_in[3];
    // d_in[4] = bk: its score contribution q0.bk is constant over m ->
    // softmax-shift-invariant, dropped entirely.

    float* out = (float*)d_out;                 // [BATCH, SEQ]
    float* q0  = (float*)d_ws;                  // BATCH*DIM floats
    float* v   = q0 + BATCH * DIM;              // BATCH*DIM floats

    qrow_kernel<<<DIM / 4, 256, 0, stream>>>(x, Wq, bq, q0);
    vvec_kernel<<<DIM / 64, 1024, 0, stream>>>(q0, Wk, v);
    score_kernel<<<dim3(SEQ / 16, BATCH), 256, 0, stream>>>(x, v, out);
    softmax_kernel<<<BATCH, 1024, 0, stream>>>(out);
}